// Round 3
// baseline (730.990 us; speedup 1.0000x reference)
//
#include <hip/hip_runtime.h>
#include <cstdint>

#define TOKENS 4096
#define DMODEL 1024
#define DFF    4096
#define NEXP   8
#define KSPLIT2 4   // K-split factor for gemm2 (K=4096 -> 4 x 1024)

typedef unsigned short u16;
typedef __attribute__((ext_vector_type(8))) short short8;   // 8 bf16 (4 VGPRs)
typedef __attribute__((ext_vector_type(4))) float f32x4;

__device__ __forceinline__ u16 f2bf(float f) {
  union { float f; uint32_t u; } c; c.f = f;
  uint32_t u = c.u;
  u += 0x7fffu + ((u >> 16) & 1u);   // round-to-nearest-even
  return (u16)(u >> 16);
}

__device__ __forceinline__ void gl_lds16(const void* g, void* l) {
  __builtin_amdgcn_global_load_lds((__attribute__((address_space(1))) void*)(g),
                                   (__attribute__((address_space(3))) void*)(l),
                                   16, 0, 0);
}

// ---------------- x fp32 -> bf16 ----------------
__global__ void cvt_x_kernel(const float* __restrict__ in, u16* __restrict__ out) {
  int i = (blockIdx.x * 256 + threadIdx.x) * 8;
  float4 a = *(const float4*)&in[i];
  float4 b = *(const float4*)&in[i + 4];
  union { u16 u[8]; uint4 v; } r;
  r.u[0] = f2bf(a.x); r.u[1] = f2bf(a.y); r.u[2] = f2bf(a.z); r.u[3] = f2bf(a.w);
  r.u[4] = f2bf(b.x); r.u[5] = f2bf(b.y); r.u[6] = f2bf(b.z); r.u[7] = f2bf(b.w);
  *(uint4*)&out[i] = r.v;
}

// ------- W [E][K][N] fp32 -> [E][N][K] bf16 (K-major for MFMA operands) -------
// fp32 LDS tile, 65-float leading dim: both store and read sides are exact
// 2-way bank aliasing (free on gfx950, m136).
__global__ void transpose_cvt_kernel(const float* __restrict__ in, u16* __restrict__ out,
                                     int K, int N) {
  __shared__ float tile[64][65];
  const int e = blockIdx.z;
  const float* ip = in + (size_t)e * K * N;
  u16* op = out + (size_t)e * K * N;
  const int kt = blockIdx.y * 64, nt = blockIdx.x * 64;
  const int tid = threadIdx.x;
#pragma unroll
  for (int i = 0; i < 4; i++) {
    int idx = tid + i * 256;          // 1024 = 64 rows x 16 col-groups
    int r = idx >> 4, cg = idx & 15;
    float4 v = *(const float4*)&ip[(size_t)(kt + r) * N + nt + cg * 4];
    tile[r][cg * 4 + 0] = v.x;
    tile[r][cg * 4 + 1] = v.y;
    tile[r][cg * 4 + 2] = v.z;
    tile[r][cg * 4 + 3] = v.w;
  }
  __syncthreads();
  // read side: rr = output row (= input col), kc = 8-wide k-chunk.
  // lanes: kc = lane&7 (128B-contig global segments per 8 lanes), rr = lane>>3.
#pragma unroll
  for (int i = 0; i < 2; i++) {
    int rr = (tid >> 3) + i * 32;
    int kc = tid & 7;
    union { u16 u[8]; uint4 v; } r8;
#pragma unroll
    for (int j = 0; j < 8; j++) r8.u[j] = f2bf(tile[kc * 8 + j][rr]);
    *(uint4*)&op[(size_t)(nt + rr) * K + kt + kc * 8] = r8.v;
  }
}

// ---------------- gating: one wave per token ----------------
__global__ void gate_kernel(const float* __restrict__ x, const float* __restrict__ Wg,
                            const float* __restrict__ bg, int* __restrict__ counts,
                            int* __restrict__ slot_tok, float* __restrict__ slot_w) {
  const int t = blockIdx.x;
  const int lane = threadIdx.x;      // 64 lanes
  const float* xr = x + (size_t)t * DMODEL;
  float acc[NEXP];
#pragma unroll
  for (int e = 0; e < NEXP; e++) acc[e] = 0.f;
#pragma unroll
  for (int i = 0; i < 4; i++) {
    int k = (lane + i * 64) * 4;
    float4 xv = *(const float4*)&xr[k];
    const float* wr = &Wg[k * NEXP];
    float xa[4] = {xv.x, xv.y, xv.z, xv.w};
#pragma unroll
    for (int j = 0; j < 4; j++)
#pragma unroll
      for (int e = 0; e < NEXP; e++) acc[e] += xa[j] * wr[j * NEXP + e];
  }
#pragma unroll
  for (int off = 32; off >= 1; off >>= 1)
#pragma unroll
    for (int e = 0; e < NEXP; e++) acc[e] += __shfl_xor(acc[e], off);
  if (lane == 0) {
#pragma unroll
    for (int e = 0; e < NEXP; e++) acc[e] += bg[e];
    int i0 = 0; float v0 = acc[0];
#pragma unroll
    for (int e = 1; e < NEXP; e++) if (acc[e] > v0) { v0 = acc[e]; i0 = e; }
    int i1 = -1; float v1 = -3.0e38f;
#pragma unroll
    for (int e = 0; e < NEXP; e++) if (e != i0 && acc[e] > v1) { v1 = acc[e]; i1 = e; }
    float ex = __expf(v1 - v0);          // v0 >= v1, stable
    float inv = 1.0f / (1.0f + ex);
    int p0 = atomicAdd(&counts[i0], 1);
    slot_tok[i0 * TOKENS + p0] = t * 2;     slot_w[i0 * TOKENS + p0] = inv;
    int p1 = atomicAdd(&counts[i1], 1);
    slot_tok[i1 * TOKENS + p1] = t * 2 + 1; slot_w[i1 * TOKENS + p1] = ex * inv;
  }
}

__global__ void prefix_kernel(const int* __restrict__ counts, int* __restrict__ base) {
  if (threadIdx.x == 0) {
    int s = 0;
    for (int e = 0; e < NEXP; e++) { base[e] = s; s += counts[e]; }
  }
}

// ---------------- GEMM1: H[base+r, :] = relu(Xgather @ W1t^T + b1), bf16 out ----------------
__global__ __launch_bounds__(256, 2) void gemm1_kernel(
    const u16* __restrict__ xb, const u16* __restrict__ w1t, const float* __restrict__ b1,
    const int* __restrict__ slot_tok, const int* __restrict__ counts,
    const int* __restrict__ base, u16* __restrict__ H) {
  const int e = blockIdx.z;
  const int cnt = counts[e];
  const int mt = blockIdx.y;
  if (mt * 128 >= cnt) return;
  const int bse = base[e];
  const int nt = blockIdx.x;
  const int tid = threadIdx.x;
  const int lane = tid & 63, wave = tid >> 6;
  const int wm = wave & 1, wn = wave >> 1;

  __shared__ u16 As[128 * 32];
  __shared__ u16 Bs[128 * 32];

  const int c0 = tid, c1 = tid + 256;           // each: row=c>>2, kchunk=c&3
  const int ar0 = mt * 128 + (c0 >> 2), ar1 = mt * 128 + (c1 >> 2);
  const int t0 = (ar0 < cnt) ? (slot_tok[e * TOKENS + ar0] >> 1) : 0;
  const int t1 = (ar1 < cnt) ? (slot_tok[e * TOKENS + ar1] >> 1) : 0;
  const u16* ag0 = xb + (size_t)t0 * DMODEL + (c0 & 3) * 8;
  const u16* ag1 = xb + (size_t)t1 * DMODEL + (c1 & 3) * 8;
  const u16* wb  = w1t + (size_t)e * DFF * DMODEL;
  const u16* bg0 = wb + (size_t)(nt * 128 + (c0 >> 2)) * DMODEL + (c0 & 3) * 8;
  const u16* bg1 = wb + (size_t)(nt * 128 + (c1 >> 2)) * DMODEL + (c1 & 3) * 8;

  f32x4 acc[4][4] = {};
  const int mr = wm * 64 + (lane & 15);
  const int nr = wn * 64 + (lane & 15);
  const int kg = (lane >> 4) * 8;

  for (int k0 = 0; k0 < DMODEL; k0 += 32) {
    __syncthreads();
    gl_lds16(ag0 + k0, &As[c0 * 8]);
    gl_lds16(ag1 + k0, &As[c1 * 8]);
    gl_lds16(bg0 + k0, &Bs[c0 * 8]);
    gl_lds16(bg1 + k0, &Bs[c1 * 8]);
    __syncthreads();
    short8 af[4], bf[4];
#pragma unroll
    for (int i = 0; i < 4; i++) af[i] = *(const short8*)&As[(mr + i * 16) * 32 + kg];
#pragma unroll
    for (int i = 0; i < 4; i++) bf[i] = *(const short8*)&Bs[(nr + i * 16) * 32 + kg];
#pragma unroll
    for (int mi = 0; mi < 4; mi++)
#pragma unroll
      for (int ni = 0; ni < 4; ni++)
        acc[mi][ni] = __builtin_amdgcn_mfma_f32_16x16x32_bf16(af[mi], bf[ni], acc[mi][ni], 0, 0, 0);
  }

  const int rq = (lane >> 4) * 4;
#pragma unroll
  for (int ni = 0; ni < 4; ni++) {
    const int n_g = nt * 128 + wn * 64 + ni * 16 + (lane & 15);
    const float bv = b1[e * DFF + n_g];
#pragma unroll
    for (int mi = 0; mi < 4; mi++)
#pragma unroll
      for (int r = 0; r < 4; r++) {
        int row = mt * 128 + wm * 64 + mi * 16 + rq + r;
        if (row < cnt) {
          float v = acc[mi][ni][r] + bv;
          H[(size_t)(bse + row) * DFF + n_g] = f2bf(v > 0.f ? v : 0.f);
        }
      }
  }
}

// ---------------- GEMM2 (K-split x4): out[tok] += w * (H @ W2t^T + b2) ----------------
__global__ __launch_bounds__(256, 2) void gemm2_kernel(
    const u16* __restrict__ H, const u16* __restrict__ w2t, const float* __restrict__ b2,
    const int* __restrict__ slot_tok, const float* __restrict__ slot_w,
    const int* __restrict__ counts, const int* __restrict__ base, float* __restrict__ out) {
  const int e = blockIdx.z;
  const int cnt = counts[e];
  const int mt = blockIdx.y;
  if (mt * 128 >= cnt) return;
  const int bse = base[e];
  const int nt = blockIdx.x & (DMODEL / 128 - 1);       // 0..7
  const int ks = blockIdx.x >> 3;                       // 0..3 K-split chunk
  const int kbeg = ks * (DFF / KSPLIT2), kend = kbeg + DFF / KSPLIT2;
  const int tid = threadIdx.x;
  const int lane = tid & 63, wave = tid >> 6;
  const int wm = wave & 1, wn = wave >> 1;

  __shared__ u16 As[128 * 32];
  __shared__ u16 Bs[128 * 32];

  const int c0 = tid, c1 = tid + 256;
  const int ar0 = mt * 128 + (c0 >> 2), ar1 = mt * 128 + (c1 >> 2);
  const int hr0 = bse + ((ar0 < cnt) ? ar0 : 0);
  const int hr1 = bse + ((ar1 < cnt) ? ar1 : 0);
  const u16* ag0 = H + (size_t)hr0 * DFF + (c0 & 3) * 8;
  const u16* ag1 = H + (size_t)hr1 * DFF + (c1 & 3) * 8;
  const u16* wb  = w2t + (size_t)e * DMODEL * DFF;
  const u16* bg0 = wb + (size_t)(nt * 128 + (c0 >> 2)) * DFF + (c0 & 3) * 8;
  const u16* bg1 = wb + (size_t)(nt * 128 + (c1 >> 2)) * DFF + (c1 & 3) * 8;

  f32x4 acc[4][4] = {};
  const int mr = wm * 64 + (lane & 15);
  const int nr = wn * 64 + (lane & 15);
  const int kg = (lane >> 4) * 8;

  for (int k0 = kbeg; k0 < kend; k0 += 32) {
    __syncthreads();
    gl_lds16(ag0 + k0, &As[c0 * 8]);
    gl_lds16(ag1 + k0, &As[c1 * 8]);
    gl_lds16(bg0 + k0, &Bs[c0 * 8]);
    gl_lds16(bg1 + k0, &Bs[c1 * 8]);
    __syncthreads();
    short8 af[4], bf[4];
#pragma unroll
    for (int i = 0; i < 4; i++) af[i] = *(const short8*)&As[(mr + i * 16) * 32 + kg];
#pragma unroll
    for (int i = 0; i < 4; i++) bf[i] = *(const short8*)&Bs[(nr + i * 16) * 32 + kg];
#pragma unroll
    for (int mi = 0; mi < 4; mi++)
#pragma unroll
      for (int ni = 0; ni < 4; ni++)
        acc[mi][ni] = __builtin_amdgcn_mfma_f32_16x16x32_bf16(af[mi], bf[ni], acc[mi][ni], 0, 0, 0);
  }

  float bv[4];
#pragma unroll
  for (int ni = 0; ni < 4; ni++)
    bv[ni] = (ks == 0) ? b2[e * DMODEL + nt * 128 + wn * 64 + ni * 16 + (lane & 15)] : 0.f;
  const int rq = (lane >> 4) * 4;
#pragma unroll
  for (int mi = 0; mi < 4; mi++)
#pragma unroll
    for (int r = 0; r < 4; r++) {
      int row = mt * 128 + wm * 64 + mi * 16 + rq + r;
      if (row < cnt) {
        int st = slot_tok[e * TOKENS + row];
        float w = slot_w[e * TOKENS + row];
        float* orow = out + (size_t)(st >> 1) * DMODEL + nt * 128 + wn * 64 + (lane & 15);
#pragma unroll
        for (int ni = 0; ni < 4; ni++)
          atomicAdd(orow + ni * 16, w * (acc[mi][ni][r] + bv[ni]));
      }
    }
}

extern "C" void kernel_launch(void* const* d_in, const int* in_sizes, int n_in,
                              void* d_out, int out_size, void* d_ws, size_t ws_size,
                              hipStream_t stream) {
  const float* x  = (const float*)d_in[0];
  const float* Wg = (const float*)d_in[1];
  const float* bg = (const float*)d_in[2];
  const float* W1 = (const float*)d_in[3];
  const float* b1 = (const float*)d_in[4];
  const float* W2 = (const float*)d_in[5];
  const float* b2 = (const float*)d_in[6];
  float* out = (float*)d_out;

  char* p = (char*)d_ws;
  int*   counts   = (int*)p;   p += 256;
  int*   base     = (int*)p;   p += 256;
  int*   slot_tok = (int*)p;   p += (size_t)NEXP * TOKENS * 4;
  float* slot_w   = (float*)p; p += (size_t)NEXP * TOKENS * 4;
  u16*   xb       = (u16*)p;   p += (size_t)TOKENS * DMODEL * 2;
  u16*   w1t      = (u16*)p;   p += (size_t)NEXP * DMODEL * DFF * 2;
  u16*   w2t      = (u16*)p;   p += (size_t)NEXP * DMODEL * DFF * 2;
  u16*   H        = (u16*)p;   p += (size_t)2 * TOKENS * DFF * 2;
  // total ws use: ~200.3 MB

  (void)hipMemsetAsync(counts, 0, 256, stream);
  (void)hipMemsetAsync(d_out, 0, (size_t)out_size * sizeof(float), stream);

  cvt_x_kernel<<<(TOKENS * DMODEL) / (256 * 8), 256, 0, stream>>>(x, xb);
  transpose_cvt_kernel<<<dim3(DFF / 64, DMODEL / 64, NEXP), 256, 0, stream>>>(W1, w1t, DMODEL, DFF);
  transpose_cvt_kernel<<<dim3(DMODEL / 64, DFF / 64, NEXP), 256, 0, stream>>>(W2, w2t, DFF, DMODEL);
  gate_kernel<<<TOKENS, 64, 0, stream>>>(x, Wg, bg, counts, slot_tok, slot_w);
  prefix_kernel<<<1, 64, 0, stream>>>(counts, base);
  gemm1_kernel<<<dim3(DFF / 128, TOKENS / 128, NEXP), 256, 0, stream>>>(
      xb, w1t, b1, slot_tok, counts, base, H);
  gemm2_kernel<<<dim3((DMODEL / 128) * KSPLIT2, TOKENS / 128, NEXP), 256, 0, stream>>>(
      H, w2t, b2, slot_tok, slot_w, counts, base, out);
}

// Round 4
// 699.332 us; speedup vs baseline: 1.0453x; 1.0453x over previous
//
#include <hip/hip_runtime.h>
#include <cstdint>

#define TOKENS 4096
#define DMODEL 1024
#define DFF    4096
#define NEXP   8
#define SLOTS  (2 * TOKENS)   // 8192 (token,expert) pairs
#define KS2    2              // K-split for gemm2 (4096 -> 2 x 2048), partial Y buffers

typedef unsigned short u16;
typedef __attribute__((ext_vector_type(8))) short short8;   // 8 bf16 (4 VGPRs)
typedef __attribute__((ext_vector_type(4))) float f32x4;

__device__ __forceinline__ u16 f2bf(float f) {
  union { float f; uint32_t u; } c; c.f = f;
  uint32_t u = c.u;
  u += 0x7fffu + ((u >> 16) & 1u);   // round-to-nearest-even
  return (u16)(u >> 16);
}

__device__ __forceinline__ void gl_lds16(const void* g, void* l) {
  __builtin_amdgcn_global_load_lds((__attribute__((address_space(1))) void*)(g),
                                   (__attribute__((address_space(3))) void*)(l),
                                   16, 0, 0);
}

// ---------------- x fp32 -> bf16 ----------------
__global__ void cvt_x_kernel(const float* __restrict__ in, u16* __restrict__ out) {
  int i = (blockIdx.x * 256 + threadIdx.x) * 8;
  float4 a = *(const float4*)&in[i];
  float4 b = *(const float4*)&in[i + 4];
  union { u16 u[8]; uint4 v; } r;
  r.u[0] = f2bf(a.x); r.u[1] = f2bf(a.y); r.u[2] = f2bf(a.z); r.u[3] = f2bf(a.w);
  r.u[4] = f2bf(b.x); r.u[5] = f2bf(b.y); r.u[6] = f2bf(b.z); r.u[7] = f2bf(b.w);
  *(uint4*)&out[i] = r.v;
}

// ------- W [E][K][N] fp32 -> [E][N][K] bf16 (K-major for MFMA operands) -------
__global__ void transpose_cvt_kernel(const float* __restrict__ in, u16* __restrict__ out,
                                     int K, int N) {
  __shared__ float tile[64][65];
  const int e = blockIdx.z;
  const float* ip = in + (size_t)e * K * N;
  u16* op = out + (size_t)e * K * N;
  const int kt = blockIdx.y * 64, nt = blockIdx.x * 64;
  const int tid = threadIdx.x;
#pragma unroll
  for (int i = 0; i < 4; i++) {
    int idx = tid + i * 256;          // 1024 = 64 rows x 16 col-groups
    int r = idx >> 4, cg = idx & 15;
    float4 v = *(const float4*)&ip[(size_t)(kt + r) * N + nt + cg * 4];
    tile[r][cg * 4 + 0] = v.x;
    tile[r][cg * 4 + 1] = v.y;
    tile[r][cg * 4 + 2] = v.z;
    tile[r][cg * 4 + 3] = v.w;
  }
  __syncthreads();
#pragma unroll
  for (int i = 0; i < 2; i++) {
    int rr = (tid >> 3) + i * 32;
    int kc = tid & 7;
    union { u16 u[8]; uint4 v; } r8;
#pragma unroll
    for (int j = 0; j < 8; j++) r8.u[j] = f2bf(tile[kc * 8 + j][rr]);
    *(uint4*)&op[(size_t)(nt + rr) * K + kt + kc * 8] = r8.v;
  }
}

// ---------------- gating: one wave per token ----------------
__global__ void gate_kernel(const float* __restrict__ x, const float* __restrict__ Wg,
                            const float* __restrict__ bg, int* __restrict__ counts,
                            int* __restrict__ slot_tok, float* __restrict__ slot_w) {
  const int t = blockIdx.x;
  const int lane = threadIdx.x;      // 64 lanes
  const float* xr = x + (size_t)t * DMODEL;
  float acc[NEXP];
#pragma unroll
  for (int e = 0; e < NEXP; e++) acc[e] = 0.f;
#pragma unroll
  for (int i = 0; i < 4; i++) {
    int k = (lane + i * 64) * 4;
    float4 xv = *(const float4*)&xr[k];
    const float* wr = &Wg[k * NEXP];
    float xa[4] = {xv.x, xv.y, xv.z, xv.w};
#pragma unroll
    for (int j = 0; j < 4; j++)
#pragma unroll
      for (int e = 0; e < NEXP; e++) acc[e] += xa[j] * wr[j * NEXP + e];
  }
#pragma unroll
  for (int off = 32; off >= 1; off >>= 1)
#pragma unroll
    for (int e = 0; e < NEXP; e++) acc[e] += __shfl_xor(acc[e], off);
  if (lane == 0) {
#pragma unroll
    for (int e = 0; e < NEXP; e++) acc[e] += bg[e];
    int i0 = 0; float v0 = acc[0];
#pragma unroll
    for (int e = 1; e < NEXP; e++) if (acc[e] > v0) { v0 = acc[e]; i0 = e; }
    int i1 = -1; float v1 = -3.0e38f;
#pragma unroll
    for (int e = 0; e < NEXP; e++) if (e != i0 && acc[e] > v1) { v1 = acc[e]; i1 = e; }
    float ex = __expf(v1 - v0);          // v0 >= v1, stable
    float inv = 1.0f / (1.0f + ex);
    int p0 = atomicAdd(&counts[i0], 1);
    slot_tok[i0 * TOKENS + p0] = t * 2;     slot_w[i0 * TOKENS + p0] = inv;
    int p1 = atomicAdd(&counts[i1], 1);
    slot_tok[i1 * TOKENS + p1] = t * 2 + 1; slot_w[i1 * TOKENS + p1] = ex * inv;
  }
}

__global__ void prefix_kernel(const int* __restrict__ counts, int* __restrict__ base) {
  if (threadIdx.x == 0) {
    int s = 0;
    for (int e = 0; e < NEXP; e++) { base[e] = s; s += counts[e]; }
  }
}

// ---------------- token -> (global slot, weight) inverse map ----------------
__global__ void build_map_kernel(const int* __restrict__ counts, const int* __restrict__ base,
                                 const int* __restrict__ slot_tok, const float* __restrict__ slot_w,
                                 int* __restrict__ tok_map, float* __restrict__ tok_w) {
  int e = blockIdx.y;
  int p = blockIdx.x * 256 + threadIdx.x;
  if (p < counts[e]) {
    int t2 = slot_tok[e * TOKENS + p];   // t*2 + which-of-top2
    tok_map[t2] = base[e] + p;
    tok_w[t2] = slot_w[e * TOKENS + p];
  }
}

// ---------------- GEMM1: H[slot, :] = relu(Xgather @ W1t^T + b1), bf16 out ----------------
// Single-barrier pipelined K-loop: prefetch k+1 AFTER the barrier, compute k.
__global__ __launch_bounds__(256, 4) void gemm1_kernel(
    const u16* __restrict__ xb, const u16* __restrict__ w1t, const float* __restrict__ b1,
    const int* __restrict__ slot_tok, const int* __restrict__ counts,
    const int* __restrict__ base, u16* __restrict__ H) {
  const int e = blockIdx.z;
  const int cnt = counts[e];
  const int mt = blockIdx.y;
  if (mt * 128 >= cnt) return;
  const int bse = base[e];
  const int nt = blockIdx.x;
  const int tid = threadIdx.x;
  const int lane = tid & 63, wave = tid >> 6;
  const int wm = wave & 1, wn = wave >> 1;

  __shared__ u16 As[2][128 * 32];
  __shared__ u16 Bs[2][128 * 32];

  const int c0 = tid, c1 = tid + 256;           // each: row=c>>2, kchunk=c&3
  const int ar0 = mt * 128 + (c0 >> 2), ar1 = mt * 128 + (c1 >> 2);
  const int t0 = (ar0 < cnt) ? (slot_tok[e * TOKENS + ar0] >> 1) : 0;
  const int t1 = (ar1 < cnt) ? (slot_tok[e * TOKENS + ar1] >> 1) : 0;
  const u16* ag0 = xb + (size_t)t0 * DMODEL + (c0 & 3) * 8;
  const u16* ag1 = xb + (size_t)t1 * DMODEL + (c1 & 3) * 8;
  const u16* wb  = w1t + (size_t)e * DFF * DMODEL;
  const u16* bg0 = wb + (size_t)(nt * 128 + (c0 >> 2)) * DMODEL + (c0 & 3) * 8;
  const u16* bg1 = wb + (size_t)(nt * 128 + (c1 >> 2)) * DMODEL + (c1 & 3) * 8;

  f32x4 acc[4][4] = {};
  const int mr = wm * 64 + (lane & 15);
  const int nr = wn * 64 + (lane & 15);
  const int kg = (lane >> 4) * 8;
  const int NIT = DMODEL / 32;

  // prologue: stage iter 0 into buffer 0
  gl_lds16(ag0, &As[0][c0 * 8]);
  gl_lds16(ag1, &As[0][c1 * 8]);
  gl_lds16(bg0, &Bs[0][c0 * 8]);
  gl_lds16(bg1, &Bs[0][c1 * 8]);

  int s = 0;
  for (int it = 0; it < NIT; ++it, s ^= 1) {
    __syncthreads();                 // drains prefetch issued one compute-phase ago
    if (it + 1 < NIT) {
      int k1 = (it + 1) * 32;
      gl_lds16(ag0 + k1, &As[s ^ 1][c0 * 8]);
      gl_lds16(ag1 + k1, &As[s ^ 1][c1 * 8]);
      gl_lds16(bg0 + k1, &Bs[s ^ 1][c0 * 8]);
      gl_lds16(bg1 + k1, &Bs[s ^ 1][c1 * 8]);
    }
    short8 af[4], bf[4];
#pragma unroll
    for (int i = 0; i < 4; i++) af[i] = *(const short8*)&As[s][(mr + i * 16) * 32 + kg];
#pragma unroll
    for (int i = 0; i < 4; i++) bf[i] = *(const short8*)&Bs[s][(nr + i * 16) * 32 + kg];
#pragma unroll
    for (int mi = 0; mi < 4; mi++)
#pragma unroll
      for (int ni = 0; ni < 4; ni++)
        acc[mi][ni] = __builtin_amdgcn_mfma_f32_16x16x32_bf16(af[mi], bf[ni], acc[mi][ni], 0, 0, 0);
  }

  const int rq = (lane >> 4) * 4;
#pragma unroll
  for (int ni = 0; ni < 4; ni++) {
    const int n_g = nt * 128 + wn * 64 + ni * 16 + (lane & 15);
    const float bv = b1[e * DFF + n_g];
#pragma unroll
    for (int mi = 0; mi < 4; mi++)
#pragma unroll
      for (int r = 0; r < 4; r++) {
        int row = mt * 128 + wm * 64 + mi * 16 + rq + r;
        if (row < cnt) {
          float v = acc[mi][ni][r] + bv;
          H[(size_t)(bse + row) * DFF + n_g] = f2bf(v > 0.f ? v : 0.f);
        }
      }
  }
}

// ------- GEMM2 (K-split x2, no atomics): Yp[ks][slot, :] = H @ W2t^T (+ b2 on ks=0) -------
__global__ __launch_bounds__(256, 4) void gemm2_kernel(
    const u16* __restrict__ H, const u16* __restrict__ w2t, const float* __restrict__ b2,
    const int* __restrict__ counts, const int* __restrict__ base, float* __restrict__ Yp) {
  const int e = blockIdx.z;
  const int cnt = counts[e];
  const int mt = blockIdx.y;
  if (mt * 128 >= cnt) return;
  const int bse = base[e];
  const int nt = blockIdx.x & (DMODEL / 128 - 1);       // 0..7
  const int ks = blockIdx.x >> 3;                       // 0..KS2-1
  const int kbeg = ks * (DFF / KS2);
  const int tid = threadIdx.x;
  const int lane = tid & 63, wave = tid >> 6;
  const int wm = wave & 1, wn = wave >> 1;

  __shared__ u16 As[2][128 * 32];
  __shared__ u16 Bs[2][128 * 32];

  const int c0 = tid, c1 = tid + 256;
  const int ar0 = mt * 128 + (c0 >> 2), ar1 = mt * 128 + (c1 >> 2);
  const int hr0 = bse + ((ar0 < cnt) ? ar0 : 0);
  const int hr1 = bse + ((ar1 < cnt) ? ar1 : 0);
  const u16* ag0 = H + (size_t)hr0 * DFF + kbeg + (c0 & 3) * 8;
  const u16* ag1 = H + (size_t)hr1 * DFF + kbeg + (c1 & 3) * 8;
  const u16* wb  = w2t + (size_t)e * DMODEL * DFF;
  const u16* bg0 = wb + (size_t)(nt * 128 + (c0 >> 2)) * DFF + kbeg + (c0 & 3) * 8;
  const u16* bg1 = wb + (size_t)(nt * 128 + (c1 >> 2)) * DFF + kbeg + (c1 & 3) * 8;

  f32x4 acc[4][4] = {};
  const int mr = wm * 64 + (lane & 15);
  const int nr = wn * 64 + (lane & 15);
  const int kg = (lane >> 4) * 8;
  const int NIT = (DFF / KS2) / 32;

  gl_lds16(ag0, &As[0][c0 * 8]);
  gl_lds16(ag1, &As[0][c1 * 8]);
  gl_lds16(bg0, &Bs[0][c0 * 8]);
  gl_lds16(bg1, &Bs[0][c1 * 8]);

  int s = 0;
  for (int it = 0; it < NIT; ++it, s ^= 1) {
    __syncthreads();
    if (it + 1 < NIT) {
      int k1 = (it + 1) * 32;
      gl_lds16(ag0 + k1, &As[s ^ 1][c0 * 8]);
      gl_lds16(ag1 + k1, &As[s ^ 1][c1 * 8]);
      gl_lds16(bg0 + k1, &Bs[s ^ 1][c0 * 8]);
      gl_lds16(bg1 + k1, &Bs[s ^ 1][c1 * 8]);
    }
    short8 af[4], bf[4];
#pragma unroll
    for (int i = 0; i < 4; i++) af[i] = *(const short8*)&As[s][(mr + i * 16) * 32 + kg];
#pragma unroll
    for (int i = 0; i < 4; i++) bf[i] = *(const short8*)&Bs[s][(nr + i * 16) * 32 + kg];
#pragma unroll
    for (int mi = 0; mi < 4; mi++)
#pragma unroll
      for (int ni = 0; ni < 4; ni++)
        acc[mi][ni] = __builtin_amdgcn_mfma_f32_16x16x32_bf16(af[mi], bf[ni], acc[mi][ni], 0, 0, 0);
  }

  float* yb = Yp + (size_t)ks * SLOTS * DMODEL;
  float bv[4];
#pragma unroll
  for (int ni = 0; ni < 4; ni++)
    bv[ni] = (ks == 0) ? b2[e * DMODEL + nt * 128 + wn * 64 + ni * 16 + (lane & 15)] : 0.f;
  const int rq = (lane >> 4) * 4;
#pragma unroll
  for (int mi = 0; mi < 4; mi++)
#pragma unroll
    for (int r = 0; r < 4; r++) {
      int row = mt * 128 + wm * 64 + mi * 16 + rq + r;
      if (row < cnt) {
        float* yrow = yb + (size_t)(bse + row) * DMODEL + nt * 128 + wn * 64 + (lane & 15);
#pragma unroll
        for (int ni = 0; ni < 4; ni++)
          yrow[ni * 16] = acc[mi][ni][r] + bv[ni];
      }
    }
}

// ---------------- combine: out[t] = w0*(Yp0[s0]+Yp1[s0]) + w1*(Yp0[s1]+Yp1[s1]) ----------------
__global__ void combine_kernel(const float* __restrict__ Yp, const int* __restrict__ tok_map,
                               const float* __restrict__ tok_w, float* __restrict__ out) {
  const int t = blockIdx.x;
  const int s0 = tok_map[2 * t], s1 = tok_map[2 * t + 1];
  const float w0 = tok_w[2 * t], w1 = tok_w[2 * t + 1];
  const int i = threadIdx.x * 4;
  const float* y0a = Yp + (size_t)s0 * DMODEL;
  const float* y0b = y0a + (size_t)SLOTS * DMODEL;
  const float* y1a = Yp + (size_t)s1 * DMODEL;
  const float* y1b = y1a + (size_t)SLOTS * DMODEL;
  float4 a = *(const float4*)&y0a[i];
  float4 b = *(const float4*)&y0b[i];
  float4 c = *(const float4*)&y1a[i];
  float4 d = *(const float4*)&y1b[i];
  float4 r;
  r.x = w0 * (a.x + b.x) + w1 * (c.x + d.x);
  r.y = w0 * (a.y + b.y) + w1 * (c.y + d.y);
  r.z = w0 * (a.z + b.z) + w1 * (c.z + d.z);
  r.w = w0 * (a.w + b.w) + w1 * (c.w + d.w);
  *(float4*)&out[(size_t)t * DMODEL + i] = r;
}

extern "C" void kernel_launch(void* const* d_in, const int* in_sizes, int n_in,
                              void* d_out, int out_size, void* d_ws, size_t ws_size,
                              hipStream_t stream) {
  const float* x  = (const float*)d_in[0];
  const float* Wg = (const float*)d_in[1];
  const float* bg = (const float*)d_in[2];
  const float* W1 = (const float*)d_in[3];
  const float* b1 = (const float*)d_in[4];
  const float* W2 = (const float*)d_in[5];
  const float* b2 = (const float*)d_in[6];
  float* out = (float*)d_out;

  char* p = (char*)d_ws;
  int*   counts   = (int*)p;   p += 256;
  int*   base     = (int*)p;   p += 256;
  int*   slot_tok = (int*)p;   p += (size_t)NEXP * TOKENS * 4;
  float* slot_w   = (float*)p; p += (size_t)NEXP * TOKENS * 4;
  int*   tok_map  = (int*)p;   p += (size_t)SLOTS * 4;
  float* tok_w    = (float*)p; p += (size_t)SLOTS * 4;
  u16*   xb       = (u16*)p;   p += (size_t)TOKENS * DMODEL * 2;
  u16*   w1t      = (u16*)p;   p += (size_t)NEXP * DMODEL * DFF * 2;   // 64 MB
  u16*   w2t      = (u16*)p;   p += (size_t)NEXP * DMODEL * DFF * 2;   // 64 MB
  u16*   H        = (u16*)p;   p += (size_t)SLOTS * DFF * 2;           // 64 MB
  // Yp (2 x 32 MB fp32 partials) ALIASES w1t: w1t is dead once gemm1 completes,
  // and gemm2 (which writes Yp) is ordered after gemm1 on the stream.
  float* Yp = (float*)w1t;
  // total ws use: ~200.8 MB

  (void)hipMemsetAsync(counts, 0, 256, stream);

  cvt_x_kernel<<<(TOKENS * DMODEL) / (256 * 8), 256, 0, stream>>>(x, xb);
  transpose_cvt_kernel<<<dim3(DFF / 64, DMODEL / 64, NEXP), 256, 0, stream>>>(W1, w1t, DMODEL, DFF);
  transpose_cvt_kernel<<<dim3(DMODEL / 64, DFF / 64, NEXP), 256, 0, stream>>>(W2, w2t, DFF, DMODEL);
  gate_kernel<<<TOKENS, 64, 0, stream>>>(x, Wg, bg, counts, slot_tok, slot_w);
  prefix_kernel<<<1, 64, 0, stream>>>(counts, base);
  build_map_kernel<<<dim3(TOKENS / 256, NEXP), 256, 0, stream>>>(
      counts, base, slot_tok, slot_w, tok_map, tok_w);
  gemm1_kernel<<<dim3(DFF / 128, TOKENS / 128, NEXP), 256, 0, stream>>>(
      xb, w1t, b1, slot_tok, counts, base, H);
  gemm2_kernel<<<dim3((DMODEL / 128) * KS2, TOKENS / 128, NEXP), 256, 0, stream>>>(
      H, w2t, b2, counts, base, Yp);
  combine_kernel<<<TOKENS, 256, 0, stream>>>(Yp, tok_map, tok_w, out);
}

// Round 5
// 668.921 us; speedup vs baseline: 1.0928x; 1.0455x over previous
//
#include <hip/hip_runtime.h>
#include <cstdint>

#define TOKENS 4096
#define DMODEL 1024
#define DFF    4096
#define NEXP   8
#define SLOTS  (2 * TOKENS)   // 8192 (token,expert) pairs
#define KS2    2              // K-split for gemm2 (4096 -> 2 x 2048), partial Y buffers
#define MAXT   71             // max total m-tiles: floor(8192/128) + 7

typedef unsigned short u16;
typedef __attribute__((ext_vector_type(8))) short short8;   // 8 bf16 (4 VGPRs)
typedef __attribute__((ext_vector_type(4))) float f32x4;

__device__ __forceinline__ u16 f2bf(float f) {
  union { float f; uint32_t u; } c; c.f = f;
  uint32_t u = c.u;
  u += 0x7fffu + ((u >> 16) & 1u);   // round-to-nearest-even
  return (u16)(u >> 16);
}

__device__ __forceinline__ void gl_lds16(const void* g, void* l) {
  __builtin_amdgcn_global_load_lds((__attribute__((address_space(1))) void*)(g),
                                   (__attribute__((address_space(3))) void*)(l),
                                   16, 0, 0);
}

// ---------------- x fp32 -> bf16 ----------------
__global__ void cvt_x_kernel(const float* __restrict__ in, u16* __restrict__ out) {
  int i = (blockIdx.x * 256 + threadIdx.x) * 8;
  float4 a = *(const float4*)&in[i];
  float4 b = *(const float4*)&in[i + 4];
  union { u16 u[8]; uint4 v; } r;
  r.u[0] = f2bf(a.x); r.u[1] = f2bf(a.y); r.u[2] = f2bf(a.z); r.u[3] = f2bf(a.w);
  r.u[4] = f2bf(b.x); r.u[5] = f2bf(b.y); r.u[6] = f2bf(b.z); r.u[7] = f2bf(b.w);
  *(uint4*)&out[i] = r.v;
}

// ------- W [E][K][N] fp32 -> [E][N][K] bf16 (K-major for MFMA operands) -------
__global__ void transpose_cvt_kernel(const float* __restrict__ in, u16* __restrict__ out,
                                     int K, int N) {
  __shared__ float tile[64][65];
  const int e = blockIdx.z;
  const float* ip = in + (size_t)e * K * N;
  u16* op = out + (size_t)e * K * N;
  const int kt = blockIdx.y * 64, nt = blockIdx.x * 64;
  const int tid = threadIdx.x;
#pragma unroll
  for (int i = 0; i < 4; i++) {
    int idx = tid + i * 256;          // 1024 = 64 rows x 16 col-groups
    int r = idx >> 4, cg = idx & 15;
    float4 v = *(const float4*)&ip[(size_t)(kt + r) * N + nt + cg * 4];
    tile[r][cg * 4 + 0] = v.x;
    tile[r][cg * 4 + 1] = v.y;
    tile[r][cg * 4 + 2] = v.z;
    tile[r][cg * 4 + 3] = v.w;
  }
  __syncthreads();
#pragma unroll
  for (int i = 0; i < 2; i++) {
    int rr = (tid >> 3) + i * 32;
    int kc = tid & 7;
    union { u16 u[8]; uint4 v; } r8;
#pragma unroll
    for (int j = 0; j < 8; j++) r8.u[j] = f2bf(tile[kc * 8 + j][rr]);
    *(uint4*)&op[(size_t)(nt + rr) * K + kt + kc * 8] = r8.v;
  }
}

// ---------------- gating: one wave per token ----------------
__global__ void gate_kernel(const float* __restrict__ x, const float* __restrict__ Wg,
                            const float* __restrict__ bg, int* __restrict__ counts,
                            int* __restrict__ slot_tok, float* __restrict__ slot_w) {
  const int t = blockIdx.x;
  const int lane = threadIdx.x;      // 64 lanes
  const float* xr = x + (size_t)t * DMODEL;
  float acc[NEXP];
#pragma unroll
  for (int e = 0; e < NEXP; e++) acc[e] = 0.f;
#pragma unroll
  for (int i = 0; i < 4; i++) {
    int k = (lane + i * 64) * 4;
    float4 xv = *(const float4*)&xr[k];
    const float* wr = &Wg[k * NEXP];
    float xa[4] = {xv.x, xv.y, xv.z, xv.w};
#pragma unroll
    for (int j = 0; j < 4; j++)
#pragma unroll
      for (int e = 0; e < NEXP; e++) acc[e] += xa[j] * wr[j * NEXP + e];
  }
#pragma unroll
  for (int off = 32; off >= 1; off >>= 1)
#pragma unroll
    for (int e = 0; e < NEXP; e++) acc[e] += __shfl_xor(acc[e], off);
  if (lane == 0) {
#pragma unroll
    for (int e = 0; e < NEXP; e++) acc[e] += bg[e];
    int i0 = 0; float v0 = acc[0];
#pragma unroll
    for (int e = 1; e < NEXP; e++) if (acc[e] > v0) { v0 = acc[e]; i0 = e; }
    int i1 = -1; float v1 = -3.0e38f;
#pragma unroll
    for (int e = 0; e < NEXP; e++) if (e != i0 && acc[e] > v1) { v1 = acc[e]; i1 = e; }
    float ex = __expf(v1 - v0);          // v0 >= v1, stable
    float inv = 1.0f / (1.0f + ex);
    int p0 = atomicAdd(&counts[i0], 1);
    slot_tok[i0 * TOKENS + p0] = t * 2;     slot_w[i0 * TOKENS + p0] = inv;
    int p1 = atomicAdd(&counts[i1], 1);
    slot_tok[i1 * TOKENS + p1] = t * 2 + 1; slot_w[i1 * TOKENS + p1] = ex * inv;
  }
}

// prefix over slots AND over m-tiles (compact GEMM work list)
__global__ void prefix_kernel(const int* __restrict__ counts, int* __restrict__ base,
                              int* __restrict__ tstart) {
  if (threadIdx.x == 0) {
    int s = 0, ts = 0;
    for (int e = 0; e < NEXP; e++) {
      base[e] = s; tstart[e] = ts;
      s += counts[e];
      ts += (counts[e] + 127) >> 7;
    }
    tstart[NEXP] = ts;
  }
}

// ---------------- token -> (global slot, weight) inverse map ----------------
__global__ void build_map_kernel(const int* __restrict__ counts, const int* __restrict__ base,
                                 const int* __restrict__ slot_tok, const float* __restrict__ slot_w,
                                 int* __restrict__ tok_map, float* __restrict__ tok_w) {
  int e = blockIdx.y;
  int p = blockIdx.x * 256 + threadIdx.x;
  if (p < counts[e]) {
    int t2 = slot_tok[e * TOKENS + p];   // t*2 + which-of-top2
    tok_map[t2] = base[e] + p;
    tok_w[t2] = slot_w[e * TOKENS + p];
  }
}

// ---------------- GEMM1: H[slot, :] = relu(Xgather @ W1t^T + b1), bf16 out ----------------
// Compact work list: blockIdx.x = trow*32 + nt, trow indexes (e,mt) via tstart scan.
__global__ __launch_bounds__(256, 4) void gemm1_kernel(
    const u16* __restrict__ xb, const u16* __restrict__ w1t, const float* __restrict__ b1,
    const int* __restrict__ slot_tok, const int* __restrict__ counts,
    const int* __restrict__ base, const int* __restrict__ tstart, u16* __restrict__ H) {
  const int nt = blockIdx.x & 31;
  const int trow = blockIdx.x >> 5;
  if (trow >= tstart[NEXP]) return;
  int e = 0;
#pragma unroll
  for (int i = 1; i < NEXP; i++) if (trow >= tstart[i]) e = i;
  const int mt = trow - tstart[e];
  const int cnt = counts[e];
  const int bse = base[e];
  const int tid = threadIdx.x;
  const int lane = tid & 63, wave = tid >> 6;
  const int wm = wave & 1, wn = wave >> 1;

  // 32 KB flat LDS: [As0 | As1 | Bs0 | Bs1], each 128x32 u16 (8 KB).
  // Epilogue reuses the whole 16384-u16 region as a 128x128 bf16 tile.
  __shared__ u16 SM[16384];

  const int c0 = tid, c1 = tid + 256;           // each: row=c>>2, kchunk=c&3
  const int ar0 = mt * 128 + (c0 >> 2), ar1 = mt * 128 + (c1 >> 2);
  const int t0 = (ar0 < cnt) ? (slot_tok[e * TOKENS + ar0] >> 1) : 0;
  const int t1 = (ar1 < cnt) ? (slot_tok[e * TOKENS + ar1] >> 1) : 0;
  const u16* ag0 = xb + (size_t)t0 * DMODEL + (c0 & 3) * 8;
  const u16* ag1 = xb + (size_t)t1 * DMODEL + (c1 & 3) * 8;
  const u16* wb  = w1t + (size_t)e * DFF * DMODEL;
  const u16* bg0 = wb + (size_t)(nt * 128 + (c0 >> 2)) * DMODEL + (c0 & 3) * 8;
  const u16* bg1 = wb + (size_t)(nt * 128 + (c1 >> 2)) * DMODEL + (c1 & 3) * 8;

  f32x4 acc[4][4] = {};
  const int mr = wm * 64 + (lane & 15);
  const int nr = wn * 64 + (lane & 15);
  const int kg = (lane >> 4) * 8;
  const int NIT = DMODEL / 32;

  // prologue: stage iter 0 into buffer 0
  gl_lds16(ag0, &SM[c0 * 8]);
  gl_lds16(ag1, &SM[c1 * 8]);
  gl_lds16(bg0, &SM[8192 + c0 * 8]);
  gl_lds16(bg1, &SM[8192 + c1 * 8]);

  int s = 0;
  for (int it = 0; it < NIT; ++it, s ^= 1) {
    __syncthreads();                 // drains prefetch issued one compute-phase ago
    if (it + 1 < NIT) {
      int k1 = (it + 1) * 32;
      gl_lds16(ag0 + k1, &SM[(s ^ 1) * 4096 + c0 * 8]);
      gl_lds16(ag1 + k1, &SM[(s ^ 1) * 4096 + c1 * 8]);
      gl_lds16(bg0 + k1, &SM[8192 + (s ^ 1) * 4096 + c0 * 8]);
      gl_lds16(bg1 + k1, &SM[8192 + (s ^ 1) * 4096 + c1 * 8]);
    }
    short8 af[4], bf[4];
#pragma unroll
    for (int i = 0; i < 4; i++) af[i] = *(const short8*)&SM[s * 4096 + (mr + i * 16) * 32 + kg];
#pragma unroll
    for (int i = 0; i < 4; i++) bf[i] = *(const short8*)&SM[8192 + s * 4096 + (nr + i * 16) * 32 + kg];
#pragma unroll
    for (int mi = 0; mi < 4; mi++)
#pragma unroll
      for (int ni = 0; ni < 4; ni++)
        acc[mi][ni] = __builtin_amdgcn_mfma_f32_16x16x32_bf16(af[mi], bf[ni], acc[mi][ni], 0, 0, 0);
  }

  // ---- epilogue: bias+relu+cvt into LDS tile, then coalesced b128 stores ----
  __syncthreads();   // all K-loop LDS reads done before overwrite
  const int rq = (lane >> 4) * 4;
#pragma unroll
  for (int ni = 0; ni < 4; ni++) {
    const int col = wn * 64 + ni * 16 + (lane & 15);
    const float bv = b1[e * DFF + nt * 128 + col];
#pragma unroll
    for (int mi = 0; mi < 4; mi++)
#pragma unroll
      for (int r = 0; r < 4; r++) {
        int row = wm * 64 + mi * 16 + rq + r;
        float v = acc[mi][ni][r] + bv;
        SM[row * 128 + col] = f2bf(v > 0.f ? v : 0.f);
      }
  }
  __syncthreads();
#pragma unroll
  for (int rep = 0; rep < 8; rep++) {
    int idx = rep * 256 + tid;          // 2048 = 128 rows x 16 chunks
    int r = idx >> 4, ch = idx & 15;
    int grow = mt * 128 + r;
    if (grow < cnt)
      *(uint4*)&H[(size_t)(bse + grow) * DFF + nt * 128 + ch * 8] =
          *(const uint4*)&SM[r * 128 + ch * 8];
  }
}

// ------- GEMM2 (K-split x2, no atomics): Yp[ks][slot, :] = H @ W2t^T (+ b2 on ks=0) -------
// Compact work list: blockIdx.x = trow*16 + (ks*8 + nt).
__global__ __launch_bounds__(256, 4) void gemm2_kernel(
    const u16* __restrict__ H, const u16* __restrict__ w2t, const float* __restrict__ b2,
    const int* __restrict__ counts, const int* __restrict__ base,
    const int* __restrict__ tstart, float* __restrict__ Yp) {
  const int nks = blockIdx.x & 15;
  const int nt = nks & 7, ks = nks >> 3;
  const int trow = blockIdx.x >> 4;
  if (trow >= tstart[NEXP]) return;
  int e = 0;
#pragma unroll
  for (int i = 1; i < NEXP; i++) if (trow >= tstart[i]) e = i;
  const int mt = trow - tstart[e];
  const int cnt = counts[e];
  const int bse = base[e];
  const int kbeg = ks * (DFF / KS2);
  const int tid = threadIdx.x;
  const int lane = tid & 63, wave = tid >> 6;
  const int wm = wave & 1, wn = wave >> 1;

  __shared__ u16 As[2][128 * 32];
  __shared__ u16 Bs[2][128 * 32];

  const int c0 = tid, c1 = tid + 256;
  const int ar0 = mt * 128 + (c0 >> 2), ar1 = mt * 128 + (c1 >> 2);
  const int hr0 = bse + ((ar0 < cnt) ? ar0 : 0);
  const int hr1 = bse + ((ar1 < cnt) ? ar1 : 0);
  const u16* ag0 = H + (size_t)hr0 * DFF + kbeg + (c0 & 3) * 8;
  const u16* ag1 = H + (size_t)hr1 * DFF + kbeg + (c1 & 3) * 8;
  const u16* wb  = w2t + (size_t)e * DMODEL * DFF;
  const u16* bg0 = wb + (size_t)(nt * 128 + (c0 >> 2)) * DFF + kbeg + (c0 & 3) * 8;
  const u16* bg1 = wb + (size_t)(nt * 128 + (c1 >> 2)) * DFF + kbeg + (c1 & 3) * 8;

  f32x4 acc[4][4] = {};
  const int mr = wm * 64 + (lane & 15);
  const int nr = wn * 64 + (lane & 15);
  const int kg = (lane >> 4) * 8;
  const int NIT = (DFF / KS2) / 32;

  gl_lds16(ag0, &As[0][c0 * 8]);
  gl_lds16(ag1, &As[0][c1 * 8]);
  gl_lds16(bg0, &Bs[0][c0 * 8]);
  gl_lds16(bg1, &Bs[0][c1 * 8]);

  int s = 0;
  for (int it = 0; it < NIT; ++it, s ^= 1) {
    __syncthreads();
    if (it + 1 < NIT) {
      int k1 = (it + 1) * 32;
      gl_lds16(ag0 + k1, &As[s ^ 1][c0 * 8]);
      gl_lds16(ag1 + k1, &As[s ^ 1][c1 * 8]);
      gl_lds16(bg0 + k1, &Bs[s ^ 1][c0 * 8]);
      gl_lds16(bg1 + k1, &Bs[s ^ 1][c1 * 8]);
    }
    short8 af[4], bf[4];
#pragma unroll
    for (int i = 0; i < 4; i++) af[i] = *(const short8*)&As[s][(mr + i * 16) * 32 + kg];
#pragma unroll
    for (int i = 0; i < 4; i++) bf[i] = *(const short8*)&Bs[s][(nr + i * 16) * 32 + kg];
#pragma unroll
    for (int mi = 0; mi < 4; mi++)
#pragma unroll
      for (int ni = 0; ni < 4; ni++)
        acc[mi][ni] = __builtin_amdgcn_mfma_f32_16x16x32_bf16(af[mi], bf[ni], acc[mi][ni], 0, 0, 0);
  }

  float* yb = Yp + (size_t)ks * SLOTS * DMODEL;
  float bv[4];
#pragma unroll
  for (int ni = 0; ni < 4; ni++)
    bv[ni] = (ks == 0) ? b2[e * DMODEL + nt * 128 + wn * 64 + ni * 16 + (lane & 15)] : 0.f;
  const int rq = (lane >> 4) * 4;
#pragma unroll
  for (int mi = 0; mi < 4; mi++)
#pragma unroll
    for (int r = 0; r < 4; r++) {
      int row = mt * 128 + wm * 64 + mi * 16 + rq + r;
      if (row < cnt) {
        float* yrow = yb + (size_t)(bse + row) * DMODEL + nt * 128 + wn * 64 + (lane & 15);
#pragma unroll
        for (int ni = 0; ni < 4; ni++)
          yrow[ni * 16] = acc[mi][ni][r] + bv[ni];
      }
    }
}

// ---------------- combine: out[t] = w0*(Yp0[s0]+Yp1[s0]) + w1*(Yp0[s1]+Yp1[s1]) ----------------
__global__ void combine_kernel(const float* __restrict__ Yp, const int* __restrict__ tok_map,
                               const float* __restrict__ tok_w, float* __restrict__ out) {
  const int t = blockIdx.x;
  const int s0 = tok_map[2 * t], s1 = tok_map[2 * t + 1];
  const float w0 = tok_w[2 * t], w1 = tok_w[2 * t + 1];
  const int i = threadIdx.x * 4;
  const float* y0a = Yp + (size_t)s0 * DMODEL;
  const float* y0b = y0a + (size_t)SLOTS * DMODEL;
  const float* y1a = Yp + (size_t)s1 * DMODEL;
  const float* y1b = y1a + (size_t)SLOTS * DMODEL;
  float4 a = *(const float4*)&y0a[i];
  float4 b = *(const float4*)&y0b[i];
  float4 c = *(const float4*)&y1a[i];
  float4 d = *(const float4*)&y1b[i];
  float4 r;
  r.x = w0 * (a.x + b.x) + w1 * (c.x + d.x);
  r.y = w0 * (a.y + b.y) + w1 * (c.y + d.y);
  r.z = w0 * (a.z + b.z) + w1 * (c.z + d.z);
  r.w = w0 * (a.w + b.w) + w1 * (c.w + d.w);
  *(float4*)&out[(size_t)t * DMODEL + i] = r;
}

extern "C" void kernel_launch(void* const* d_in, const int* in_sizes, int n_in,
                              void* d_out, int out_size, void* d_ws, size_t ws_size,
                              hipStream_t stream) {
  const float* x  = (const float*)d_in[0];
  const float* Wg = (const float*)d_in[1];
  const float* bg = (const float*)d_in[2];
  const float* W1 = (const float*)d_in[3];
  const float* b1 = (const float*)d_in[4];
  const float* W2 = (const float*)d_in[5];
  const float* b2 = (const float*)d_in[6];
  float* out = (float*)d_out;

  char* p = (char*)d_ws;
  int*   counts   = (int*)p;   p += 256;
  int*   base     = (int*)p;   p += 256;
  int*   tstart   = (int*)p;   p += 256;
  int*   slot_tok = (int*)p;   p += (size_t)NEXP * TOKENS * 4;
  float* slot_w   = (float*)p; p += (size_t)NEXP * TOKENS * 4;
  int*   tok_map  = (int*)p;   p += (size_t)SLOTS * 4;
  float* tok_w    = (float*)p; p += (size_t)SLOTS * 4;
  u16*   xb       = (u16*)p;   p += (size_t)TOKENS * DMODEL * 2;
  u16*   w1t      = (u16*)p;   p += (size_t)NEXP * DMODEL * DFF * 2;   // 64 MB
  u16*   w2t      = (u16*)p;   p += (size_t)NEXP * DMODEL * DFF * 2;   // 64 MB
  u16*   H        = (u16*)p;   p += (size_t)SLOTS * DFF * 2;           // 64 MB
  // Yp (2 x 32 MB fp32 partials) ALIASES w1t: w1t is dead once gemm1 completes,
  // and gemm2 (which writes Yp) is ordered after gemm1 on the stream.
  float* Yp = (float*)w1t;
  // total ws use: ~200.8 MB

  (void)hipMemsetAsync(counts, 0, 256, stream);

  cvt_x_kernel<<<(TOKENS * DMODEL) / (256 * 8), 256, 0, stream>>>(x, xb);
  transpose_cvt_kernel<<<dim3(DFF / 64, DMODEL / 64, NEXP), 256, 0, stream>>>(W1, w1t, DMODEL, DFF);
  transpose_cvt_kernel<<<dim3(DMODEL / 64, DFF / 64, NEXP), 256, 0, stream>>>(W2, w2t, DFF, DMODEL);
  gate_kernel<<<TOKENS, 64, 0, stream>>>(x, Wg, bg, counts, slot_tok, slot_w);
  prefix_kernel<<<1, 64, 0, stream>>>(counts, base, tstart);
  build_map_kernel<<<dim3(TOKENS / 256, NEXP), 256, 0, stream>>>(
      counts, base, slot_tok, slot_w, tok_map, tok_w);
  gemm1_kernel<<<MAXT * 32, 256, 0, stream>>>(
      xb, w1t, b1, slot_tok, counts, base, tstart, H);
  gemm2_kernel<<<MAXT * 16, 256, 0, stream>>>(
      H, w2t, b2, counts, base, tstart, Yp);
  combine_kernel<<<TOKENS, 256, 0, stream>>>(Yp, tok_map, tok_w, out);
}